// Round 2
// baseline (3307.957 us; speedup 1.0000x reference)
//
#include <hip/hip_runtime.h>
#include <math.h>

#define NG   500000
#define DM   256
#define NH   8
#define DHD  32
#define DFF  1024
#define NLAY 2
#define PED  63
#define VSF  0.0625f
#define EPSF 1e-5f
#define UP   4928      // padded max unique rows (77*64)
#define MAXU 4913      // 17^3 hard bound from data distribution
#define NQT  77        // ceil(UP/64)
#define NDBLK 7813     // ceil(NG/64)
#define SCL  0.17677669529663687f  // 1/sqrt(32)

typedef short bf16x8 __attribute__((ext_vector_type(8)));
typedef float f32x4 __attribute__((ext_vector_type(4)));

__device__ __forceinline__ float lrelu(float v){ return v >= 0.f ? v : 0.01f*v; }

// f32 -> bf16 (RNE), bit pattern as short
__device__ __forceinline__ short f2b(float f){
  unsigned u = __float_as_uint(f);
  return (short)((u + 0x7fffu + ((u >> 16) & 1u)) >> 16);
}

__device__ __forceinline__ f32x4 mfma16(bf16x8 a, bf16x8 b, f32x4 c){
  return __builtin_amdgcn_mfma_f32_16x16x32_bf16(a, b, c, 0, 0, 0);
}

__device__ __forceinline__ float embed_elem(float cx, float cy, float cz, int j){
  if (j == 0) return cx;
  if (j == 1) return cy;
  if (j == 2) return cz;
  int q = j - 3;
  int f = q / 6;
  int r = q - f*6;
  int c = r % 3;
  float base = (c==0)?cx:((c==1)?cy:cz);
  float xf = base * (float)(1u << f);
  return (r < 3) ? sinf(xf) : cosf(xf);
}

__device__ __forceinline__ float wred(float v){
  #pragma unroll
  for (int o = 32; o > 0; o >>= 1) v += __shfl_xor(v, o);
  return v;
}

// ---------------- prep: counts + voxel coords ----------------
__global__ void zero_kernel(int* p, int n){
  int i = blockIdx.x*blockDim.x + threadIdx.x;
  if (i < n) p[i] = 0;
}

__global__ void prep_kernel(const float* __restrict__ centres, const int* __restrict__ inv,
                            int* __restrict__ counts, float* __restrict__ uv){
  for (int i = blockIdx.x*blockDim.x + threadIdx.x; i < NG; i += gridDim.x*blockDim.x){
    int v = inv[i];
    atomicAdd(&counts[v], 1);
    float vx = rintf(centres[i*3]   * 16.f) * VSF;   // exact: /VS == *16
    float vy = rintf(centres[i*3+1] * 16.f) * VSF;
    float vz = rintf(centres[i*3+2] * 16.f) * VSF;
    uv[v*3] = vx; uv[v*3+1] = vy; uv[v*3+2] = vz;    // benign same-value race
  }
}

// single-block exclusive scan over counts[0..U)  (U <= 8192)
__global__ void scan_kernel(const int* __restrict__ counts, int* __restrict__ offs,
                            const int* __restrict__ pU){
  const int U = *pU;
  const int CH = 8;
  __shared__ int tot[1024];
  int tid = threadIdx.x;
  int base = tid * CH;
  int c[CH];
  int s = 0;
  #pragma unroll
  for (int i = 0; i < CH; ++i){
    int idx = base + i;
    int v = (idx < U) ? counts[idx] : 0;
    c[i] = s;
    s += v;
  }
  tot[tid] = s;
  __syncthreads();
  for (int o = 1; o < 1024; o <<= 1){
    int v = 0;
    if (tid >= o) v = tot[tid - o];
    __syncthreads();
    tot[tid] += v;
    __syncthreads();
  }
  int excl = tot[tid] - s;
  #pragma unroll
  for (int i = 0; i < CH; ++i){
    int idx = base + i;
    if (idx < U) offs[idx] = excl + c[i];
  }
}

__global__ void scatter_kernel(const int* __restrict__ inv, const int* __restrict__ offs,
                               int* __restrict__ cursor, int* __restrict__ gidx){
  for (int i = blockIdx.x*blockDim.x + threadIdx.x; i < NG; i += gridDim.x*blockDim.x){
    int v = inv[i];
    int p = atomicAdd(&cursor[v], 1);
    gidx[offs[v] + p] = i;
  }
}

// ---------------- weight conversion to bf16 (once per launch) ----------------
__global__ void cvt_weights(const float* __restrict__ ipw, const float* __restrict__ opw,
                            const float* __restrict__ l1w, const float* __restrict__ l2w,
                            const float* __restrict__ dw1, const float* __restrict__ dw2,
                            short* ipwb, short* opwb, short* l1wb, short* l2wb,
                            short* dw2b, short* dw1bb, short* dw1ab){
  int i = blockIdx.x*256 + threadIdx.x;
  switch (blockIdx.y){
    case 0: if (i < 2*768*256)  ipwb[i] = f2b(ipw[i]); break;
    case 1: if (i < 2*256*256)  opwb[i] = f2b(opw[i]); break;
    case 2: if (i < 2*1024*256) l1wb[i] = f2b(l1w[i]); break;
    case 3: if (i < 2*256*1024) l2wb[i] = f2b(l2w[i]); break;
    case 4: if (i < 256*256)    dw2b[i] = f2b(dw2[i]); break;
    case 5: if (i < 256*256){ int r = i>>8, c = i&255; dw1bb[i] = f2b(dw1[r*319 + 63 + c]); } break;
    case 6: if (i < 256*64){  int r = i>>6, c = i&63;  dw1ab[i] = f2b(c < 63 ? dw1[r*319 + c] : 0.f); } break;
  }
}

// ---------------- per-voxel: feature sum + PE MLP -> x = agg + pe (f32) ----------------
__global__ __launch_bounds__(256) void agg_pe_kernel(const float* __restrict__ feats,
   const int* __restrict__ gidx, const int* __restrict__ offs, const int* __restrict__ counts,
   const float* __restrict__ uv, const float* __restrict__ pw1, const float* __restrict__ pb1,
   const float* __restrict__ pw2, const float* __restrict__ pb2,
   float* __restrict__ x, const int* __restrict__ pU){
  const int U = *pU;
  __shared__ __align__(16) float e[PED];
  __shared__ __align__(16) float h[DM];
  const int t = threadIdx.x;
  for (int u = blockIdx.x; u < U; u += gridDim.x){
    const int o0 = offs[u], cnt = counts[u];
    float sum = 0.f;
    for (int j = 0; j < cnt; ++j)
      sum += feats[(size_t)gidx[o0+j]*DM + t];
    if (t < PED){
      float cx = uv[u*3], cy = uv[u*3+1], cz = uv[u*3+2];
      e[t] = embed_elem(cx, cy, cz, t);
    }
    __syncthreads();
    float a1 = pb1[t];
    const float* w1 = pw1 + t*PED;
    for (int k = 0; k < PED; ++k) a1 += w1[k]*e[k];
    h[t] = lrelu(a1);
    __syncthreads();
    float a2 = pb2[t];
    const float* w2 = pw2 + (size_t)t*DM;
    for (int k = 0; k < DM; k += 4){
      float4 w = *reinterpret_cast<const float4*>(w2+k);
      float4 hv = *reinterpret_cast<const float4*>(&h[k]);
      a2 += w.x*hv.x + w.y*hv.y + w.z*hv.z + w.w*hv.w;
    }
    x[(size_t)u*DM + t] = sum + a2;
    __syncthreads();
  }
}

// ---------------- bf16 MFMA GEMM: C[M][Nn] = act(A_f32[M][K] * Bbf[Nn][K]^T + bias) (+res) ----------------
// block: 256 thr = 4 waves; tile 64 rows x 64 cols; wave w owns rows [16w,16w+16), cols n0..n0+64
template<int ACT, bool HASRES>
__global__ __launch_bounds__(256) void gemm_bf(const float* __restrict__ A,
    const short* __restrict__ Bbf, const float* __restrict__ bias,
    const float* __restrict__ res, float* __restrict__ C,
    const int K, const int Nn, const int* __restrict__ pU){
  const int M = *pU;
  const int r0 = blockIdx.x * 64;
  if (r0 >= M) return;
  const int n0 = blockIdx.y * 64;
  __shared__ __align__(16) short Al[64*32];
  const int tid = threadIdx.x;
  const int wid = tid >> 6, lane = tid & 63;
  const int l15 = lane & 15, l4 = lane >> 4;
  f32x4 acc[4];
  #pragma unroll
  for (int nt = 0; nt < 4; ++nt) acc[nt] = (f32x4){0.f,0.f,0.f,0.f};
  const int nk = K >> 5;
  const int srow = tid >> 2, se8 = (tid & 3) * 8;
  const int arowc = min(r0 + srow, M-1);
  for (int kc = 0; kc < nk; ++kc){
    // stage A chunk [64][32] as bf16, XOR-swizzled rows
    {
      const float* ap = A + (size_t)arowc*K + kc*32 + se8;
      f32x4 a0 = *(const f32x4*)ap;
      f32x4 a1 = *(const f32x4*)(ap + 4);
      bf16x8 av;
      av[0]=f2b(a0[0]); av[1]=f2b(a0[1]); av[2]=f2b(a0[2]); av[3]=f2b(a0[3]);
      av[4]=f2b(a1[0]); av[5]=f2b(a1[1]); av[6]=f2b(a1[2]); av[7]=f2b(a1[3]);
      *(bf16x8*)&Al[(srow*32 + se8) ^ ((srow & 7) << 3)] = av;
    }
    __syncthreads();
    const int ar = 16*wid + l15;
    bf16x8 af = *(const bf16x8*)&Al[(ar*32 + 8*l4) ^ ((ar & 7) << 3)];
    #pragma unroll
    for (int nt = 0; nt < 4; ++nt){
      const short* bp = Bbf + (size_t)(n0 + 16*nt + l15)*K + kc*32 + 8*l4;
      bf16x8 bfr = *(const bf16x8*)bp;
      acc[nt] = mfma16(af, bfr, acc[nt]);
    }
    __syncthreads();
  }
  #pragma unroll
  for (int nt = 0; nt < 4; ++nt){
    const int col = n0 + 16*nt + l15;
    const float bv = bias[col];
    #pragma unroll
    for (int r = 0; r < 4; ++r){
      const int row = r0 + 16*wid + 4*l4 + r;
      if (row < M){
        float v = acc[nt][r] + bv;
        if (ACT == 1) v = fmaxf(v, 0.f);
        if (HASRES) v += res[(size_t)row*Nn + col];
        C[(size_t)row*Nn + col] = v;
      }
    }
  }
}

// ---------------- MFMA flash attention (swapped S^T = K*Q^T), 4 waves x 16 queries ----------------
__global__ __launch_bounds__(256) void attn_mfma(const float* __restrict__ qkv,
                                                 float* __restrict__ y, const int* __restrict__ pU){
  const int U = *pU;
  const int bid = blockIdx.x;
  const int h = bid & 7, qt = bid >> 3;
  const int q0 = qt * 64;
  const int tid = threadIdx.x;
  const int wid = tid >> 6, lane = tid & 63;
  const int l15 = lane & 15, l4 = lane >> 4;
  __shared__ __align__(16) short Kl[64*32];     // K tile, row-major [key][dh], swizzled
  __shared__ __align__(16) short Vt[32*64];     // V^T tile [dh][key], swizzled
  __shared__ __align__(16) short Pl[4][64*16];  // per-wave P^T [key][q]

  // Q fragment (B operand), scale folded, bf16
  const int qrow = min(q0 + 16*wid + l15, U-1);
  const float* qp = qkv + (size_t)qrow*768 + h*DHD + 8*l4;
  bf16x8 qf;
  {
    f32x4 q0v = *(const f32x4*)qp;
    f32x4 q1v = *(const f32x4*)(qp + 4);
    qf[0]=f2b(q0v[0]*SCL); qf[1]=f2b(q0v[1]*SCL); qf[2]=f2b(q0v[2]*SCL); qf[3]=f2b(q0v[3]*SCL);
    qf[4]=f2b(q1v[0]*SCL); qf[5]=f2b(q1v[1]*SCL); qf[6]=f2b(q1v[2]*SCL); qf[7]=f2b(q1v[3]*SCL);
  }
  f32x4 o0 = (f32x4){0.f,0.f,0.f,0.f}, o1 = (f32x4){0.f,0.f,0.f,0.f};
  float mrun = -INFINITY, lrun = 0.f;
  const int srow = tid >> 2, se8 = (tid & 3) * 8;
  const int ntile = (U + 63) >> 6;
  for (int kt = 0; kt < ntile; ++kt){
    const int kb = kt * 64;
    // stage K [64][32] and V^T [32][64] (bf16, swizzled)
    {
      const int krow = min(kb + srow, U-1);
      const float* kp = qkv + (size_t)krow*768 + DM + h*DHD + se8;
      f32x4 k0 = *(const f32x4*)kp;
      f32x4 k1 = *(const f32x4*)(kp + 4);
      bf16x8 kv;
      kv[0]=f2b(k0[0]); kv[1]=f2b(k0[1]); kv[2]=f2b(k0[2]); kv[3]=f2b(k0[3]);
      kv[4]=f2b(k1[0]); kv[5]=f2b(k1[1]); kv[6]=f2b(k1[2]); kv[7]=f2b(k1[3]);
      *(bf16x8*)&Kl[(srow*32 + se8) ^ ((srow & 7) << 3)] = kv;
      const float* vp = qkv + (size_t)krow*768 + 2*DM + h*DHD + se8;
      f32x4 v0 = *(const f32x4*)vp;
      f32x4 v1 = *(const f32x4*)(vp + 4);
      #pragma unroll
      for (int j = 0; j < 8; ++j){
        const int d = se8 + j;
        const float vv = (j < 4) ? v0[j & 3] : v1[j & 3];
        Vt[(d*64 + srow) ^ ((d & 7) << 3)] = f2b(vv);
      }
    }
    __syncthreads();
    // S^T = K * Q^T : 4 MFMAs; lane holds S^T[16nt+4*l4+r][q=l15]
    float s[16];
    #pragma unroll
    for (int nt = 0; nt < 4; ++nt){
      const int row = 16*nt + l15;
      bf16x8 kf = *(const bf16x8*)&Kl[(row*32 + 8*l4) ^ ((row & 7) << 3)];
      f32x4 d = mfma16(kf, qf, (f32x4){0.f,0.f,0.f,0.f});
      const int kbase = kb + 16*nt + 4*l4;
      #pragma unroll
      for (int r = 0; r < 4; ++r)
        s[nt*4 + r] = (kbase + r < U) ? d[r] : -INFINITY;
    }
    // online softmax; stats lane-local for column q = l15
    float cm = s[0];
    #pragma unroll
    for (int i = 1; i < 16; ++i) cm = fmaxf(cm, s[i]);
    cm = fmaxf(cm, __shfl_xor(cm, 16));
    cm = fmaxf(cm, __shfl_xor(cm, 32));
    const float mnew = fmaxf(mrun, cm);
    const float f = __expf(mrun - mnew);
    float ls = 0.f;
    #pragma unroll
    for (int i = 0; i < 16; ++i){ s[i] = __expf(s[i] - mnew); ls += s[i]; }
    ls += __shfl_xor(ls, 16);
    ls += __shfl_xor(ls, 32);
    lrun = lrun * f + ls;
    o0 = o0 * f; o1 = o1 * f;
    mrun = mnew;
    // write P^T (bf16) to per-wave LDS
    #pragma unroll
    for (int nt = 0; nt < 4; ++nt)
      #pragma unroll
      for (int r = 0; r < 4; ++r){
        const int row = 16*nt + 4*l4 + r;
        Pl[wid][(row*16 + l15) ^ (((row >> 2) & 3) << 2)] = f2b(s[nt*4 + r]);
      }
    __syncthreads();
    // O^T += V^T * P^T
    #pragma unroll
    for (int kc = 0; kc < 2; ++kc){
      bf16x8 pf;
      #pragma unroll
      for (int j = 0; j < 8; ++j){
        const int row = 32*kc + 8*l4 + j;
        pf[j] = Pl[wid][(row*16 + l15) ^ (((row >> 2) & 3) << 2)];
      }
      {
        const int row = l15;
        bf16x8 vf = *(const bf16x8*)&Vt[(row*64 + 32*kc + 8*l4) ^ ((row & 7) << 3)];
        o0 = mfma16(vf, pf, o0);
      }
      {
        const int row = 16 + l15;
        bf16x8 vf = *(const bf16x8*)&Vt[(row*64 + 32*kc + 8*l4) ^ ((row & 7) << 3)];
        o1 = mfma16(vf, pf, o1);
      }
    }
    __syncthreads();
  }
  // epilogue: lane holds O^T[16ndt+4*l4+r][q=l15]
  const float invl = 1.f / lrun;
  const int qg = q0 + 16*wid + l15;
  if (qg < U){
    float* yp = y + (size_t)qg*DM + h*DHD;
    #pragma unroll
    for (int r = 0; r < 4; ++r){
      yp[4*l4 + r]      = o0[r] * invl;
      yp[16 + 4*l4 + r] = o1[r] * invl;
    }
  }
}

// ---------------- LayerNorm (row per block-iteration) ----------------
__global__ __launch_bounds__(256) void ln_kernel(const float* __restrict__ in,
    const float* __restrict__ w, const float* __restrict__ b,
    float* __restrict__ out, const int* __restrict__ pU){
  const int U = *pU;
  const int t = threadIdx.x;
  const int wid = t >> 6;
  __shared__ float red[4];
  for (int u = blockIdx.x; u < U; u += gridDim.x){
    float v = in[(size_t)u*DM + t];
    float s = wred(v);
    if ((t & 63) == 0) red[wid] = s;
    __syncthreads();
    float mean = (red[0]+red[1]+red[2]+red[3]) * (1.f/DM);
    __syncthreads();
    float d = v - mean;
    float sq = wred(d*d);
    if ((t & 63) == 0) red[wid] = sq;
    __syncthreads();
    float var = (red[0]+red[1]+red[2]+red[3]) * (1.f/DM);
    out[(size_t)u*DM + t] = d * (1.0f/sqrtf(var + EPSF)) * w[t] + b[t];
    __syncthreads();
  }
}

// ---------------- per-gaussian delta MLP (MFMA both layers) + final output ----------------
// layer1: h = lrelu(rc[voxel] + embed @ W1a^T)   (rc = x@W1b^T + b1 precomputed per voxel)
// layer2: out = x[voxel] + b2 + h @ W2^T
__global__ __launch_bounds__(256) void delta_mfma(const float* __restrict__ centres,
   const int* __restrict__ inv, const float* __restrict__ x, const float* __restrict__ rc,
   const short* __restrict__ w1abf, const short* __restrict__ w2bf,
   const float* __restrict__ db2, float* __restrict__ out){
  __shared__ __align__(16) float cs[64][3];
  __shared__ int ivl[64];
  __shared__ __align__(16) short el[64*64];     // embed tile [g][64], swizzled
  __shared__ __align__(16) short hl[64*256];    // hidden tile [g][256], swizzled
  const int tid = threadIdx.x;
  const int wid = tid >> 6, lane = tid & 63;
  const int l15 = lane & 15, l4 = lane >> 4;
  const int g0 = blockIdx.x * 64;
  if (tid < 64){
    const int gid = min(g0 + tid, NG-1);
    cs[tid][0] = centres[gid*3];
    cs[tid][1] = centres[gid*3+1];
    cs[tid][2] = centres[gid*3+2];
    ivl[tid] = inv[gid];
  }
  __syncthreads();
  for (int i = tid; i < 64*64; i += 256){
    const int g = i >> 6, j = i & 63;
    const float v = (j < PED) ? embed_elem(cs[g][0], cs[g][1], cs[g][2], j) : 0.f;
    el[(g*64 + j) ^ ((g & 7) << 3)] = f2b(v);
  }
  __syncthreads();
  // layer 1: wave w owns gaussians [16w, 16w+16)
  bf16x8 ef[2];
  #pragma unroll
  for (int kc = 0; kc < 2; ++kc){
    const int row = 16*wid + l15;
    ef[kc] = *(const bf16x8*)&el[(row*64 + kc*32 + 8*l4) ^ ((row & 7) << 3)];
  }
  const int glb = 16*wid + 4*l4;  // + r
  #pragma unroll
  for (int nt = 0; nt < 16; ++nt){
    f32x4 a;
    #pragma unroll
    for (int r = 0; r < 4; ++r)
      a[r] = rc[(size_t)ivl[glb + r]*DM + 16*nt + l15];
    #pragma unroll
    for (int kc = 0; kc < 2; ++kc){
      const bf16x8 bfr = *(const bf16x8*)&w1abf[(16*nt + l15)*64 + kc*32 + 8*l4];
      a = mfma16(ef[kc], bfr, a);
    }
    #pragma unroll
    for (int r = 0; r < 4; ++r){
      const int row = glb + r;
      hl[(row*256 + 16*nt + l15) ^ ((row & 7) << 3)] = f2b(lrelu(a[r]));
    }
  }
  __syncthreads();
  // layer 2
  bf16x8 hf[8];
  #pragma unroll
  for (int kc = 0; kc < 8; ++kc){
    const int row = 16*wid + l15;
    hf[kc] = *(const bf16x8*)&hl[(row*256 + kc*32 + 8*l4) ^ ((row & 7) << 3)];
  }
  f32x4 acc[16];
  #pragma unroll
  for (int nt = 0; nt < 16; ++nt){
    const float bv = db2[16*nt + l15];
    #pragma unroll
    for (int r = 0; r < 4; ++r)
      acc[nt][r] = x[(size_t)ivl[glb + r]*DM + 16*nt + l15] + bv;
  }
  #pragma unroll
  for (int kc = 0; kc < 8; ++kc){
    #pragma unroll
    for (int nt = 0; nt < 16; ++nt){
      const bf16x8 bfr = *(const bf16x8*)&w2bf[(size_t)(16*nt + l15)*256 + kc*32 + 8*l4];
      acc[nt] = mfma16(hf[kc], bfr, acc[nt]);
    }
  }
  #pragma unroll
  for (int nt = 0; nt < 16; ++nt){
    #pragma unroll
    for (int r = 0; r < 4; ++r){
      const int g = g0 + glb + r;
      if (g < NG)
        out[(size_t)g*DM + 16*nt + l15] = acc[nt][r];
    }
  }
}

extern "C" void kernel_launch(void* const* d_in, const int* in_sizes, int n_in,
                              void* d_out, int out_size, void* d_ws, size_t ws_size,
                              hipStream_t stream){
  (void)in_sizes; (void)n_in; (void)out_size; (void)ws_size;
  const float* centres = (const float*)d_in[0];
  const float* feats   = (const float*)d_in[1];
  const int*   inv     = (const int*)d_in[2];
  const int*   pU      = (const int*)d_in[3];
  const float* ipw = (const float*)d_in[4];
  const float* ipb = (const float*)d_in[5];
  const float* opw = (const float*)d_in[6];
  const float* opb = (const float*)d_in[7];
  const float* l1w = (const float*)d_in[8];
  const float* l1b = (const float*)d_in[9];
  const float* l2w = (const float*)d_in[10];
  const float* l2b = (const float*)d_in[11];
  const float* n1w = (const float*)d_in[12];
  const float* n1b = (const float*)d_in[13];
  const float* n2w = (const float*)d_in[14];
  const float* n2b = (const float*)d_in[15];
  const float* pw1 = (const float*)d_in[16];
  const float* pb1 = (const float*)d_in[17];
  const float* pw2 = (const float*)d_in[18];
  const float* pb2 = (const float*)d_in[19];
  const float* dw1 = (const float*)d_in[20];
  const float* db1 = (const float*)d_in[21];
  const float* dw2 = (const float*)d_in[22];
  const float* db2 = (const float*)d_in[23];
  float* out = (float*)d_out;

  char* ws = (char*)d_ws;
  size_t off = 0;
  auto take = [&](size_t bytes)->char*{
    char* p = ws + off; off += (bytes + 255) & ~(size_t)255; return p;
  };
  float* xb   = (float*)take((size_t)UP*DM*4);
  float* yb   = (float*)take((size_t)UP*DM*4);
  float* big  = (float*)take((size_t)UP*DFF*4);   // qkv [U][768] / pre-LN [U][256] / ffn hidden [U][1024]
  float* rcb  = (float*)take((size_t)UP*DM*4);
  float* uv   = (float*)take((size_t)UP*3*4);
  int* counts = (int*)take((size_t)2*UP*4);
  int* cursor = counts + UP;
  int* offs   = (int*)take((size_t)UP*4);
  int* gidx   = (int*)take((size_t)NG*4);
  short* ipwbf  = (short*)take((size_t)2*768*256*2);
  short* opwbf  = (short*)take((size_t)2*256*256*2);
  short* l1wbf  = (short*)take((size_t)2*1024*256*2);
  short* l2wbf  = (short*)take((size_t)2*256*1024*2);
  short* dw2bf  = (short*)take((size_t)256*256*2);
  short* dw1bbf = (short*)take((size_t)256*256*2);
  short* dw1abf = (short*)take((size_t)256*64*2);

  zero_kernel<<<(2*UP + 255)/256, 256, 0, stream>>>(counts, 2*UP);
  prep_kernel<<<1024, 256, 0, stream>>>(centres, inv, counts, uv);
  scan_kernel<<<1, 1024, 0, stream>>>(counts, offs, pU);
  scatter_kernel<<<1024, 256, 0, stream>>>(inv, offs, cursor, gidx);
  cvt_weights<<<dim3(2048, 7), 256, 0, stream>>>(ipw, opw, l1w, l2w, dw1, dw2,
                                                 ipwbf, opwbf, l1wbf, l2wbf,
                                                 dw2bf, dw1bbf, dw1abf);
  agg_pe_kernel<<<2048, 256, 0, stream>>>(feats, gidx, offs, counts, uv,
                                          pw1, pb1, pw2, pb2, xb, pU);

  for (int l = 0; l < NLAY; ++l){
    // qkv = x @ Wi^T + bi -> big [U][768]
    gemm_bf<0,false><<<dim3(NQT,12), 256, 0, stream>>>(xb, ipwbf + (size_t)l*768*256,
        ipb + (size_t)l*768, nullptr, big, DM, 3*DM, pU);
    // flash attention -> yb [U][256]
    attn_mfma<<<8*NQT, 256, 0, stream>>>(big, yb, pU);
    // pre-LN = x + o@Wo^T + bo -> big
    gemm_bf<0,true><<<dim3(NQT,4), 256, 0, stream>>>(yb, opwbf + (size_t)l*256*256,
        opb + (size_t)l*DM, xb, big, DM, DM, pU);
    ln_kernel<<<1024, 256, 0, stream>>>(big, n1w + (size_t)l*DM, n1b + (size_t)l*DM, xb, pU);
    // ffn1: relu(x @ W1^T + b1) -> big [U][1024]
    gemm_bf<1,false><<<dim3(NQT,16), 256, 0, stream>>>(xb, l1wbf + (size_t)l*1024*256,
        l1b + (size_t)l*DFF, nullptr, big, DM, DFF, pU);
    // pre-LN2 = x + ff @ W2^T + b2 -> yb
    gemm_bf<0,true><<<dim3(NQT,4), 256, 0, stream>>>(big, l2wbf + (size_t)l*256*1024,
        l2b + (size_t)l*DM, xb, yb, DFF, DM, pU);
    ln_kernel<<<1024, 256, 0, stream>>>(yb, n2w + (size_t)l*DM, n2b + (size_t)l*DM, xb, pU);
  }

  // rc = x @ dm_w1[:,63:]^T + dm_b1  (per-voxel rec contribution to delta layer1)
  gemm_bf<0,false><<<dim3(NQT,4), 256, 0, stream>>>(xb, dw1bbf, db1, nullptr, rcb, DM, DM, pU);
  // per-gaussian delta MLP + out = rec + delta
  delta_mfma<<<NDBLK, 256, 0, stream>>>(centres, inv, xb, rcb, dw1abf, dw2bf, db2, out);
}

// Round 3
// 2653.873 us; speedup vs baseline: 1.2465x; 1.2465x over previous
//
#include <hip/hip_runtime.h>
#include <math.h>

#define NG   500000
#define DM   256
#define NH   8
#define DHD  32
#define DFF  1024
#define NLAY 2
#define PED  63
#define VSF  0.0625f
#define EPSF 1e-5f
#define UP   4928      // padded max unique rows (77*64)
#define MAXU 4913      // 17^3 hard bound from data distribution
#define NQT  77        // ceil(UP/64)
#define NDBLK 7813     // ceil(NG/64)
#define SCL  0.17677669529663687f  // 1/sqrt(32)

typedef short bf16x8 __attribute__((ext_vector_type(8)));
typedef float f32x4 __attribute__((ext_vector_type(4)));

__device__ __forceinline__ float lrelu(float v){ return v >= 0.f ? v : 0.01f*v; }

// f32 -> bf16 (RNE), bit pattern as short
__device__ __forceinline__ short f2b(float f){
  unsigned u = __float_as_uint(f);
  return (short)((u + 0x7fffu + ((u >> 16) & 1u)) >> 16);
}

__device__ __forceinline__ f32x4 mfma16(bf16x8 a, bf16x8 b, f32x4 c){
  return __builtin_amdgcn_mfma_f32_16x16x32_bf16(a, b, c, 0, 0, 0);
}

__device__ __forceinline__ float embed_elem(float cx, float cy, float cz, int j){
  if (j == 0) return cx;
  if (j == 1) return cy;
  if (j == 2) return cz;
  int q = j - 3;
  int f = q / 6;
  int r = q - f*6;
  int c = r % 3;
  float base = (c==0)?cx:((c==1)?cy:cz);
  float xf = base * (float)(1u << f);
  return (r < 3) ? sinf(xf) : cosf(xf);
}

__device__ __forceinline__ float wred(float v){
  #pragma unroll
  for (int o = 32; o > 0; o >>= 1) v += __shfl_xor(v, o);
  return v;
}

// ---------------- prep: counts + voxel coords ----------------
__global__ void zero_kernel(int* p, int n){
  int i = blockIdx.x*blockDim.x + threadIdx.x;
  if (i < n) p[i] = 0;
}

__global__ void prep_kernel(const float* __restrict__ centres, const int* __restrict__ inv,
                            int* __restrict__ counts, float* __restrict__ uv){
  for (int i = blockIdx.x*blockDim.x + threadIdx.x; i < NG; i += gridDim.x*blockDim.x){
    int v = inv[i];
    atomicAdd(&counts[v], 1);
    float vx = rintf(centres[i*3]   * 16.f) * VSF;   // exact: /VS == *16
    float vy = rintf(centres[i*3+1] * 16.f) * VSF;
    float vz = rintf(centres[i*3+2] * 16.f) * VSF;
    uv[v*3] = vx; uv[v*3+1] = vy; uv[v*3+2] = vz;    // benign same-value race
  }
}

// single-block exclusive scan over counts[0..U)  (U <= 8192)
__global__ void scan_kernel(const int* __restrict__ counts, int* __restrict__ offs,
                            const int* __restrict__ pU){
  const int U = *pU;
  const int CH = 8;
  __shared__ int tot[1024];
  int tid = threadIdx.x;
  int base = tid * CH;
  int c[CH];
  int s = 0;
  #pragma unroll
  for (int i = 0; i < CH; ++i){
    int idx = base + i;
    int v = (idx < U) ? counts[idx] : 0;
    c[i] = s;
    s += v;
  }
  tot[tid] = s;
  __syncthreads();
  for (int o = 1; o < 1024; o <<= 1){
    int v = 0;
    if (tid >= o) v = tot[tid - o];
    __syncthreads();
    tot[tid] += v;
    __syncthreads();
  }
  int excl = tot[tid] - s;
  #pragma unroll
  for (int i = 0; i < CH; ++i){
    int idx = base + i;
    if (idx < U) offs[idx] = excl + c[i];
  }
}

__global__ void scatter_kernel(const int* __restrict__ inv, const int* __restrict__ offs,
                               int* __restrict__ cursor, int* __restrict__ gidx){
  for (int i = blockIdx.x*blockDim.x + threadIdx.x; i < NG; i += gridDim.x*blockDim.x){
    int v = inv[i];
    int p = atomicAdd(&cursor[v], 1);
    gidx[offs[v] + p] = i;
  }
}

// ---------------- weight conversion to bf16 (once per launch) ----------------
__global__ void cvt_weights(const float* __restrict__ ipw, const float* __restrict__ opw,
                            const float* __restrict__ l1w, const float* __restrict__ l2w,
                            const float* __restrict__ dw1, const float* __restrict__ dw2,
                            short* ipwb, short* opwb, short* l1wb, short* l2wb,
                            short* dw2b, short* dw1bb, short* dw1ab){
  int i = blockIdx.x*256 + threadIdx.x;
  switch (blockIdx.y){
    case 0: if (i < 2*768*256)  ipwb[i] = f2b(ipw[i]); break;
    case 1: if (i < 2*256*256)  opwb[i] = f2b(opw[i]); break;
    case 2: if (i < 2*1024*256) l1wb[i] = f2b(l1w[i]); break;
    case 3: if (i < 2*256*1024) l2wb[i] = f2b(l2w[i]); break;
    case 4: if (i < 256*256)    dw2b[i] = f2b(dw2[i]); break;
    case 5: if (i < 256*256){ int r = i>>8, c = i&255; dw1bb[i] = f2b(dw1[r*319 + 63 + c]); } break;
    case 6: if (i < 256*64){  int r = i>>6, c = i&63;  dw1ab[i] = f2b(c < 63 ? dw1[r*319 + c] : 0.f); } break;
  }
}

// ---------------- per-voxel: feature sum (LDS-staged indices, 4 rows in flight) + PE MLP ----------------
__global__ __launch_bounds__(256) void agg_pe_kernel(const float* __restrict__ feats,
   const int* __restrict__ gidx, const int* __restrict__ offs, const int* __restrict__ counts,
   const float* __restrict__ uv, const float* __restrict__ pw1, const float* __restrict__ pb1,
   const float* __restrict__ pw2, const float* __restrict__ pb2,
   float* __restrict__ x, const int* __restrict__ pU){
  const int U = *pU;
  __shared__ int gl[512];
  __shared__ __align__(16) float4 red[256];   // 4 KB: per-thread partials, then column sums
  __shared__ __align__(16) float e[PED];
  __shared__ __align__(16) float h[DM];
  const int t = threadIdx.x;
  const int c4 = t & 63;          // float4 column group
  const int rr = t >> 6;          // row slot 0..3
  for (int u = blockIdx.x; u < U; u += gridDim.x){
    const int o0 = offs[u], cnt = counts[u];
    float4 s = {0.f,0.f,0.f,0.f};
    for (int base = 0; base < cnt; base += 512){
      const int cc = min(cnt - base, 512);
      __syncthreads();                               // gl reuse guard
      for (int j = t; j < cc; j += 256) gl[j] = gidx[o0 + base + j];
      __syncthreads();
      int j = rr;
      for (; j + 8 <= cc; j += 8){                   // 2 rows in flight per thread
        const int r0 = gl[j], r1 = gl[j+4];
        float4 v0 = *reinterpret_cast<const float4*>(&feats[(size_t)r0*DM + c4*4]);
        float4 v1 = *reinterpret_cast<const float4*>(&feats[(size_t)r1*DM + c4*4]);
        s.x += v0.x + v1.x; s.y += v0.y + v1.y;
        s.z += v0.z + v1.z; s.w += v0.w + v1.w;
      }
      for (; j < cc; j += 4){
        float4 v0 = *reinterpret_cast<const float4*>(&feats[(size_t)gl[j]*DM + c4*4]);
        s.x += v0.x; s.y += v0.y; s.z += v0.z; s.w += v0.w;
      }
    }
    red[t] = s;
    if (t < PED)
      e[t] = embed_elem(uv[u*3], uv[u*3+1], uv[u*3+2], t);
    __syncthreads();
    if (rr == 0){
      float4 a = red[c4], b = red[64+c4], c = red[128+c4], d = red[192+c4];
      a.x += b.x + c.x + d.x; a.y += b.y + c.y + d.y;
      a.z += b.z + c.z + d.z; a.w += b.w + c.w + d.w;
      red[c4] = a;
    }
    __syncthreads();
    const float sum = reinterpret_cast<const float*>(red)[t];   // column t total
    // PE MLP (thread t owns output column t)
    float a1 = pb1[t];
    const float* w1 = pw1 + t*PED;
    for (int k = 0; k < PED; ++k) a1 += w1[k]*e[k];
    h[t] = lrelu(a1);
    __syncthreads();
    float a2 = pb2[t];
    const float* w2 = pw2 + (size_t)t*DM;
    for (int k = 0; k < DM; k += 4){
      float4 w = *reinterpret_cast<const float4*>(w2+k);
      float4 hv = *reinterpret_cast<const float4*>(&h[k]);
      a2 += w.x*hv.x + w.y*hv.y + w.z*hv.z + w.w*hv.w;
    }
    x[(size_t)u*DM + t] = sum + a2;
    __syncthreads();
  }
}

// ---------------- bf16 MFMA GEMM: C[M][Nn] = act(A_f32[M][K] * Bbf[Nn][K]^T + bias) (+res) ----------------
template<int ACT, bool HASRES>
__global__ __launch_bounds__(256) void gemm_bf(const float* __restrict__ A,
    const short* __restrict__ Bbf, const float* __restrict__ bias,
    const float* __restrict__ res, float* __restrict__ C,
    const int K, const int Nn, const int* __restrict__ pU){
  const int M = *pU;
  const int r0 = blockIdx.x * 64;
  if (r0 >= M) return;
  const int n0 = blockIdx.y * 64;
  __shared__ __align__(16) short Al[64*32];
  const int tid = threadIdx.x;
  const int wid = tid >> 6, lane = tid & 63;
  const int l15 = lane & 15, l4 = lane >> 4;
  f32x4 acc[4];
  #pragma unroll
  for (int nt = 0; nt < 4; ++nt) acc[nt] = (f32x4){0.f,0.f,0.f,0.f};
  const int nk = K >> 5;
  const int srow = tid >> 2, se8 = (tid & 3) * 8;
  const int arowc = min(r0 + srow, M-1);
  for (int kc = 0; kc < nk; ++kc){
    {
      const float* ap = A + (size_t)arowc*K + kc*32 + se8;
      f32x4 a0 = *(const f32x4*)ap;
      f32x4 a1 = *(const f32x4*)(ap + 4);
      bf16x8 av;
      av[0]=f2b(a0[0]); av[1]=f2b(a0[1]); av[2]=f2b(a0[2]); av[3]=f2b(a0[3]);
      av[4]=f2b(a1[0]); av[5]=f2b(a1[1]); av[6]=f2b(a1[2]); av[7]=f2b(a1[3]);
      *(bf16x8*)&Al[(srow*32 + se8) ^ ((srow & 7) << 3)] = av;
    }
    __syncthreads();
    const int ar = 16*wid + l15;
    bf16x8 af = *(const bf16x8*)&Al[(ar*32 + 8*l4) ^ ((ar & 7) << 3)];
    #pragma unroll
    for (int nt = 0; nt < 4; ++nt){
      const short* bp = Bbf + (size_t)(n0 + 16*nt + l15)*K + kc*32 + 8*l4;
      bf16x8 bfr = *(const bf16x8*)bp;
      acc[nt] = mfma16(af, bfr, acc[nt]);
    }
    __syncthreads();
  }
  #pragma unroll
  for (int nt = 0; nt < 4; ++nt){
    const int col = n0 + 16*nt + l15;
    const float bv = bias[col];
    #pragma unroll
    for (int r = 0; r < 4; ++r){
      const int row = r0 + 16*wid + 4*l4 + r;
      if (row < M){
        float v = acc[nt][r] + bv;
        if (ACT == 1) v = fmaxf(v, 0.f);
        if (HASRES) v += res[(size_t)row*Nn + col];
        C[(size_t)row*Nn + col] = v;
      }
    }
  }
}

// ---------------- MFMA flash attention (swapped S^T = K*Q^T), 4 waves x 16 queries ----------------
__global__ __launch_bounds__(256) void attn_mfma(const float* __restrict__ qkv,
                                                 float* __restrict__ y, const int* __restrict__ pU){
  const int U = *pU;
  const int bid = blockIdx.x;
  const int h = bid & 7, qt = bid >> 3;
  const int q0 = qt * 64;
  const int tid = threadIdx.x;
  const int wid = tid >> 6, lane = tid & 63;
  const int l15 = lane & 15, l4 = lane >> 4;
  __shared__ __align__(16) short Kl[64*32];     // K tile, row-major [key][dh], swizzled
  __shared__ __align__(16) short Vt[32*64];     // V^T tile [dh][key], swizzled
  __shared__ __align__(16) short Pl[4][64*16];  // per-wave P^T [key][q]

  const int qrow = min(q0 + 16*wid + l15, U-1);
  const float* qp = qkv + (size_t)qrow*768 + h*DHD + 8*l4;
  bf16x8 qf;
  {
    f32x4 q0v = *(const f32x4*)qp;
    f32x4 q1v = *(const f32x4*)(qp + 4);
    qf[0]=f2b(q0v[0]*SCL); qf[1]=f2b(q0v[1]*SCL); qf[2]=f2b(q0v[2]*SCL); qf[3]=f2b(q0v[3]*SCL);
    qf[4]=f2b(q1v[0]*SCL); qf[5]=f2b(q1v[1]*SCL); qf[6]=f2b(q1v[2]*SCL); qf[7]=f2b(q1v[3]*SCL);
  }
  f32x4 o0 = (f32x4){0.f,0.f,0.f,0.f}, o1 = (f32x4){0.f,0.f,0.f,0.f};
  float mrun = -INFINITY, lrun = 0.f;
  const int srow = tid >> 2, se8 = (tid & 3) * 8;
  const int ntile = (U + 63) >> 6;
  for (int kt = 0; kt < ntile; ++kt){
    const int kb = kt * 64;
    {
      const int krow = min(kb + srow, U-1);
      const float* kp = qkv + (size_t)krow*768 + DM + h*DHD + se8;
      f32x4 k0 = *(const f32x4*)kp;
      f32x4 k1 = *(const f32x4*)(kp + 4);
      bf16x8 kv;
      kv[0]=f2b(k0[0]); kv[1]=f2b(k0[1]); kv[2]=f2b(k0[2]); kv[3]=f2b(k0[3]);
      kv[4]=f2b(k1[0]); kv[5]=f2b(k1[1]); kv[6]=f2b(k1[2]); kv[7]=f2b(k1[3]);
      *(bf16x8*)&Kl[(srow*32 + se8) ^ ((srow & 7) << 3)] = kv;
      const float* vp = qkv + (size_t)krow*768 + 2*DM + h*DHD + se8;
      f32x4 v0 = *(const f32x4*)vp;
      f32x4 v1 = *(const f32x4*)(vp + 4);
      #pragma unroll
      for (int j = 0; j < 8; ++j){
        const int d = se8 + j;
        const float vv = (j < 4) ? v0[j & 3] : v1[j & 3];
        Vt[(d*64 + srow) ^ ((d & 7) << 3)] = f2b(vv);
      }
    }
    __syncthreads();
    float s[16];
    #pragma unroll
    for (int nt = 0; nt < 4; ++nt){
      const int row = 16*nt + l15;
      bf16x8 kf = *(const bf16x8*)&Kl[(row*32 + 8*l4) ^ ((row & 7) << 3)];
      f32x4 d = mfma16(kf, qf, (f32x4){0.f,0.f,0.f,0.f});
      const int kbase = kb + 16*nt + 4*l4;
      #pragma unroll
      for (int r = 0; r < 4; ++r)
        s[nt*4 + r] = (kbase + r < U) ? d[r] : -INFINITY;
    }
    float cm = s[0];
    #pragma unroll
    for (int i = 1; i < 16; ++i) cm = fmaxf(cm, s[i]);
    cm = fmaxf(cm, __shfl_xor(cm, 16));
    cm = fmaxf(cm, __shfl_xor(cm, 32));
    const float mnew = fmaxf(mrun, cm);
    const float f = __expf(mrun - mnew);
    float ls = 0.f;
    #pragma unroll
    for (int i = 0; i < 16; ++i){ s[i] = __expf(s[i] - mnew); ls += s[i]; }
    ls += __shfl_xor(ls, 16);
    ls += __shfl_xor(ls, 32);
    lrun = lrun * f + ls;
    o0 = o0 * f; o1 = o1 * f;
    mrun = mnew;
    #pragma unroll
    for (int nt = 0; nt < 4; ++nt)
      #pragma unroll
      for (int r = 0; r < 4; ++r){
        const int row = 16*nt + 4*l4 + r;
        Pl[wid][(row*16 + l15) ^ (((row >> 2) & 3) << 2)] = f2b(s[nt*4 + r]);
      }
    __syncthreads();
    #pragma unroll
    for (int kc = 0; kc < 2; ++kc){
      bf16x8 pf;
      #pragma unroll
      for (int j = 0; j < 8; ++j){
        const int row = 32*kc + 8*l4 + j;
        pf[j] = Pl[wid][(row*16 + l15) ^ (((row >> 2) & 3) << 2)];
      }
      {
        const int row = l15;
        bf16x8 vf = *(const bf16x8*)&Vt[(row*64 + 32*kc + 8*l4) ^ ((row & 7) << 3)];
        o0 = mfma16(vf, pf, o0);
      }
      {
        const int row = 16 + l15;
        bf16x8 vf = *(const bf16x8*)&Vt[(row*64 + 32*kc + 8*l4) ^ ((row & 7) << 3)];
        o1 = mfma16(vf, pf, o1);
      }
    }
    __syncthreads();
  }
  const float invl = 1.f / lrun;
  const int qg = q0 + 16*wid + l15;
  if (qg < U){
    float* yp = y + (size_t)qg*DM + h*DHD;
    #pragma unroll
    for (int r = 0; r < 4; ++r){
      yp[4*l4 + r]      = o0[r] * invl;
      yp[16 + 4*l4 + r] = o1[r] * invl;
    }
  }
}

// ---------------- LayerNorm ----------------
__global__ __launch_bounds__(256) void ln_kernel(const float* __restrict__ in,
    const float* __restrict__ w, const float* __restrict__ b,
    float* __restrict__ out, const int* __restrict__ pU){
  const int U = *pU;
  const int t = threadIdx.x;
  const int wid = t >> 6;
  __shared__ float red[4];
  for (int u = blockIdx.x; u < U; u += gridDim.x){
    float v = in[(size_t)u*DM + t];
    float s = wred(v);
    if ((t & 63) == 0) red[wid] = s;
    __syncthreads();
    float mean = (red[0]+red[1]+red[2]+red[3]) * (1.f/DM);
    __syncthreads();
    float d = v - mean;
    float sq = wred(d*d);
    if ((t & 63) == 0) red[wid] = sq;
    __syncthreads();
    float var = (red[0]+red[1]+red[2]+red[3]) * (1.f/DM);
    out[(size_t)u*DM + t] = d * (1.0f/sqrtf(var + EPSF)) * w[t] + b[t];
    __syncthreads();
  }
}

// ---------------- per-gaussian delta MLP (MFMA both layers) + final output ----------------
__global__ __launch_bounds__(256) void delta_mfma(const float* __restrict__ centres,
   const int* __restrict__ inv, const float* __restrict__ x, const float* __restrict__ rc,
   const short* __restrict__ w1abf, const short* __restrict__ w2bf,
   const float* __restrict__ db2, float* __restrict__ out){
  __shared__ __align__(16) float cs[64][3];
  __shared__ int ivl[64];
  __shared__ __align__(16) short el[64*64];
  __shared__ __align__(16) short hl[64*256];
  const int tid = threadIdx.x;
  const int wid = tid >> 6, lane = tid & 63;
  const int l15 = lane & 15, l4 = lane >> 4;
  const int g0 = blockIdx.x * 64;
  if (tid < 64){
    const int gid = min(g0 + tid, NG-1);
    cs[tid][0] = centres[gid*3];
    cs[tid][1] = centres[gid*3+1];
    cs[tid][2] = centres[gid*3+2];
    ivl[tid] = inv[gid];
  }
  __syncthreads();
  for (int i = tid; i < 64*64; i += 256){
    const int g = i >> 6, j = i & 63;
    const float v = (j < PED) ? embed_elem(cs[g][0], cs[g][1], cs[g][2], j) : 0.f;
    el[(g*64 + j) ^ ((g & 7) << 3)] = f2b(v);
  }
  __syncthreads();
  bf16x8 ef[2];
  #pragma unroll
  for (int kc = 0; kc < 2; ++kc){
    const int row = 16*wid + l15;
    ef[kc] = *(const bf16x8*)&el[(row*64 + kc*32 + 8*l4) ^ ((row & 7) << 3)];
  }
  const int glb = 16*wid + 4*l4;
  #pragma unroll
  for (int nt = 0; nt < 16; ++nt){
    f32x4 a;
    #pragma unroll
    for (int r = 0; r < 4; ++r)
      a[r] = rc[(size_t)ivl[glb + r]*DM + 16*nt + l15];
    #pragma unroll
    for (int kc = 0; kc < 2; ++kc){
      const bf16x8 bfr = *(const bf16x8*)&w1abf[(16*nt + l15)*64 + kc*32 + 8*l4];
      a = mfma16(ef[kc], bfr, a);
    }
    #pragma unroll
    for (int r = 0; r < 4; ++r){
      const int row = glb + r;
      hl[(row*256 + 16*nt + l15) ^ ((row & 7) << 3)] = f2b(lrelu(a[r]));
    }
  }
  __syncthreads();
  bf16x8 hf[8];
  #pragma unroll
  for (int kc = 0; kc < 8; ++kc){
    const int row = 16*wid + l15;
    hf[kc] = *(const bf16x8*)&hl[(row*256 + kc*32 + 8*l4) ^ ((row & 7) << 3)];
  }
  f32x4 acc[16];
  #pragma unroll
  for (int nt = 0; nt < 16; ++nt){
    const float bv = db2[16*nt + l15];
    #pragma unroll
    for (int r = 0; r < 4; ++r)
      acc[nt][r] = x[(size_t)ivl[glb + r]*DM + 16*nt + l15] + bv;
  }
  #pragma unroll
  for (int kc = 0; kc < 8; ++kc){
    #pragma unroll
    for (int nt = 0; nt < 16; ++nt){
      const bf16x8 bfr = *(const bf16x8*)&w2bf[(size_t)(16*nt + l15)*256 + kc*32 + 8*l4];
      acc[nt] = mfma16(hf[kc], bfr, acc[nt]);
    }
  }
  #pragma unroll
  for (int nt = 0; nt < 16; ++nt){
    #pragma unroll
    for (int r = 0; r < 4; ++r){
      const int g = g0 + glb + r;
      if (g < NG)
        out[(size_t)g*DM + 16*nt + l15] = acc[nt][r];
    }
  }
}

extern "C" void kernel_launch(void* const* d_in, const int* in_sizes, int n_in,
                              void* d_out, int out_size, void* d_ws, size_t ws_size,
                              hipStream_t stream){
  (void)in_sizes; (void)n_in; (void)out_size; (void)ws_size;
  const float* centres = (const float*)d_in[0];
  const float* feats   = (const float*)d_in[1];
  const int*   inv     = (const int*)d_in[2];
  const int*   pU      = (const int*)d_in[3];
  const float* ipw = (const float*)d_in[4];
  const float* ipb = (const float*)d_in[5];
  const float* opw = (const float*)d_in[6];
  const float* opb = (const float*)d_in[7];
  const float* l1w = (const float*)d_in[8];
  const float* l1b = (const float*)d_in[9];
  const float* l2w = (const float*)d_in[10];
  const float* l2b = (const float*)d_in[11];
  const float* n1w = (const float*)d_in[12];
  const float* n1b = (const float*)d_in[13];
  const float* n2w = (const float*)d_in[14];
  const float* n2b = (const float*)d_in[15];
  const float* pw1 = (const float*)d_in[16];
  const float* pb1 = (const float*)d_in[17];
  const float* pw2 = (const float*)d_in[18];
  const float* pb2 = (const float*)d_in[19];
  const float* dw1 = (const float*)d_in[20];
  const float* db1 = (const float*)d_in[21];
  const float* dw2 = (const float*)d_in[22];
  const float* db2 = (const float*)d_in[23];
  float* out = (float*)d_out;

  char* ws = (char*)d_ws;
  size_t off = 0;
  auto take = [&](size_t bytes)->char*{
    char* p = ws + off; off += (bytes + 255) & ~(size_t)255; return p;
  };
  float* xb   = (float*)take((size_t)UP*DM*4);
  float* yb   = (float*)take((size_t)UP*DM*4);
  float* big  = (float*)take((size_t)UP*DFF*4);
  float* rcb  = (float*)take((size_t)UP*DM*4);
  float* uv   = (float*)take((size_t)UP*3*4);
  int* counts = (int*)take((size_t)2*UP*4);
  int* cursor = counts + UP;
  int* offs   = (int*)take((size_t)UP*4);
  int* gidx   = (int*)take((size_t)NG*4);
  short* ipwbf  = (short*)take((size_t)2*768*256*2);
  short* opwbf  = (short*)take((size_t)2*256*256*2);
  short* l1wbf  = (short*)take((size_t)2*1024*256*2);
  short* l2wbf  = (short*)take((size_t)2*256*1024*2);
  short* dw2bf  = (short*)take((size_t)256*256*2);
  short* dw1bbf = (short*)take((size_t)256*256*2);
  short* dw1abf = (short*)take((size_t)256*64*2);

  zero_kernel<<<(2*UP + 255)/256, 256, 0, stream>>>(counts, 2*UP);
  prep_kernel<<<1024, 256, 0, stream>>>(centres, inv, counts, uv);
  scan_kernel<<<1, 1024, 0, stream>>>(counts, offs, pU);
  scatter_kernel<<<1024, 256, 0, stream>>>(inv, offs, cursor, gidx);
  cvt_weights<<<dim3(2048, 7), 256, 0, stream>>>(ipw, opw, l1w, l2w, dw1, dw2,
                                                 ipwbf, opwbf, l1wbf, l2wbf,
                                                 dw2bf, dw1bbf, dw1abf);
  agg_pe_kernel<<<MAXU, 256, 0, stream>>>(feats, gidx, offs, counts, uv,
                                          pw1, pb1, pw2, pb2, xb, pU);

  for (int l = 0; l < NLAY; ++l){
    gemm_bf<0,false><<<dim3(NQT,12), 256, 0, stream>>>(xb, ipwbf + (size_t)l*768*256,
        ipb + (size_t)l*768, nullptr, big, DM, 3*DM, pU);
    attn_mfma<<<8*NQT, 256, 0, stream>>>(big, yb, pU);
    gemm_bf<0,true><<<dim3(NQT,4), 256, 0, stream>>>(yb, opwbf + (size_t)l*256*256,
        opb + (size_t)l*DM, xb, big, DM, DM, pU);
    ln_kernel<<<1024, 256, 0, stream>>>(big, n1w + (size_t)l*DM, n1b + (size_t)l*DM, xb, pU);
    gemm_bf<1,false><<<dim3(NQT,16), 256, 0, stream>>>(xb, l1wbf + (size_t)l*1024*256,
        l1b + (size_t)l*DFF, nullptr, big, DM, DFF, pU);
    gemm_bf<0,true><<<dim3(NQT,4), 256, 0, stream>>>(big, l2wbf + (size_t)l*256*1024,
        l2b + (size_t)l*DM, xb, yb, DFF, DM, pU);
    ln_kernel<<<1024, 256, 0, stream>>>(yb, n2w + (size_t)l*DM, n2b + (size_t)l*DM, xb, pU);
  }

  gemm_bf<0,false><<<dim3(NQT,4), 256, 0, stream>>>(xb, dw1bbf, db1, nullptr, rcb, DM, DM, pU);
  delta_mfma<<<NDBLK, 256, 0, stream>>>(centres, inv, xb, rcb, dw1abf, dw2bf, db2, out);
}

// Round 4
// 2472.946 us; speedup vs baseline: 1.3377x; 1.0732x over previous
//
#include <hip/hip_runtime.h>
#include <math.h>

#define NG   500000
#define DM   256
#define NH   8
#define DHD  32
#define DFF  1024
#define NLAY 2
#define PED  63
#define VSF  0.0625f
#define EPSF 1e-5f
#define UP   4928      // padded max unique rows (77*64)
#define MAXU 4913      // 17^3 hard bound from data distribution
#define NQT  77        // ceil(UP/64)
#define NDBLK 7813     // ceil(NG/64)
#define SCL  0.17677669529663687f  // 1/sqrt(32)

typedef short bf16x8 __attribute__((ext_vector_type(8)));
typedef float f32x4 __attribute__((ext_vector_type(4)));

__device__ __forceinline__ float lrelu(float v){ return v >= 0.f ? v : 0.01f*v; }

// f32 -> bf16 (RNE), bit pattern as short
__device__ __forceinline__ short f2b(float f){
  unsigned u = __float_as_uint(f);
  return (short)((u + 0x7fffu + ((u >> 16) & 1u)) >> 16);
}

__device__ __forceinline__ f32x4 mfma16(bf16x8 a, bf16x8 b, f32x4 c){
  return __builtin_amdgcn_mfma_f32_16x16x32_bf16(a, b, c, 0, 0, 0);
}

__device__ __forceinline__ float embed_elem(float cx, float cy, float cz, int j){
  if (j == 0) return cx;
  if (j == 1) return cy;
  if (j == 2) return cz;
  int q = j - 3;
  int f = q / 6;
  int r = q - f*6;
  int c = r % 3;
  float base = (c==0)?cx:((c==1)?cy:cz);
  float xf = base * (float)(1u << f);
  return (r < 3) ? sinf(xf) : cosf(xf);
}

__device__ __forceinline__ float wred(float v){
  #pragma unroll
  for (int o = 32; o > 0; o >>= 1) v += __shfl_xor(v, o);
  return v;
}

// ---------------- prep: counts + voxel coords ----------------
__global__ void zero_kernel(int* p, int n){
  int i = blockIdx.x*blockDim.x + threadIdx.x;
  if (i < n) p[i] = 0;
}

__global__ void prep_kernel(const float* __restrict__ centres, const int* __restrict__ inv,
                            int* __restrict__ counts, float* __restrict__ uv){
  for (int i = blockIdx.x*blockDim.x + threadIdx.x; i < NG; i += gridDim.x*blockDim.x){
    int v = inv[i];
    atomicAdd(&counts[v], 1);
    float vx = rintf(centres[i*3]   * 16.f) * VSF;   // exact: /VS == *16
    float vy = rintf(centres[i*3+1] * 16.f) * VSF;
    float vz = rintf(centres[i*3+2] * 16.f) * VSF;
    uv[v*3] = vx; uv[v*3+1] = vy; uv[v*3+2] = vz;    // benign same-value race
  }
}

// single-block exclusive scan over counts[0..U)  (U <= 8192)
__global__ void scan_kernel(const int* __restrict__ counts, int* __restrict__ offs,
                            const int* __restrict__ pU){
  const int U = *pU;
  const int CH = 8;
  __shared__ int tot[1024];
  int tid = threadIdx.x;
  int base = tid * CH;
  int c[CH];
  int s = 0;
  #pragma unroll
  for (int i = 0; i < CH; ++i){
    int idx = base + i;
    int v = (idx < U) ? counts[idx] : 0;
    c[i] = s;
    s += v;
  }
  tot[tid] = s;
  __syncthreads();
  for (int o = 1; o < 1024; o <<= 1){
    int v = 0;
    if (tid >= o) v = tot[tid - o];
    __syncthreads();
    tot[tid] += v;
    __syncthreads();
  }
  int excl = tot[tid] - s;
  #pragma unroll
  for (int i = 0; i < CH; ++i){
    int idx = base + i;
    if (idx < U) offs[idx] = excl + c[i];
  }
}

__global__ void scatter_kernel(const int* __restrict__ inv, const int* __restrict__ offs,
                               int* __restrict__ cursor, int* __restrict__ gidx){
  for (int i = blockIdx.x*blockDim.x + threadIdx.x; i < NG; i += gridDim.x*blockDim.x){
    int v = inv[i];
    int p = atomicAdd(&cursor[v], 1);
    gidx[offs[v] + p] = i;
  }
}

// ---------------- weight conversion to bf16 (once per launch) ----------------
__global__ void cvt_weights(const float* __restrict__ ipw, const float* __restrict__ opw,
                            const float* __restrict__ l1w, const float* __restrict__ l2w,
                            const float* __restrict__ dw1, const float* __restrict__ dw2,
                            short* ipwb, short* opwb, short* l1wb, short* l2wb,
                            short* dw2b, short* dw1bb, short* dw1ab){
  int i = blockIdx.x*256 + threadIdx.x;
  switch (blockIdx.y){
    case 0: if (i < 2*768*256)  ipwb[i] = f2b(ipw[i]); break;
    case 1: if (i < 2*256*256)  opwb[i] = f2b(opw[i]); break;
    case 2: if (i < 2*1024*256) l1wb[i] = f2b(l1w[i]); break;
    case 3: if (i < 2*256*1024) l2wb[i] = f2b(l2w[i]); break;
    case 4: if (i < 256*256)    dw2b[i] = f2b(dw2[i]); break;
    case 5: if (i < 256*256){ int r = i>>8, c = i&255; dw1bb[i] = f2b(dw1[r*319 + 63 + c]); } break;
    case 6: if (i < 256*64){  int r = i>>6, c = i&63;  dw1ab[i] = f2b(c < 63 ? dw1[r*319 + c] : 0.f); } break;
  }
}

// ---------------- per-voxel: feature sum (LDS-staged indices, 4 rows in flight) + PE MLP ----------------
__global__ __launch_bounds__(256) void agg_pe_kernel(const float* __restrict__ feats,
   const int* __restrict__ gidx, const int* __restrict__ offs, const int* __restrict__ counts,
   const float* __restrict__ uv, const float* __restrict__ pw1, const float* __restrict__ pb1,
   const float* __restrict__ pw2, const float* __restrict__ pb2,
   float* __restrict__ x, const int* __restrict__ pU){
  const int U = *pU;
  __shared__ int gl[512];
  __shared__ __align__(16) float4 red[256];   // 4 KB: per-thread partials, then column sums
  __shared__ __align__(16) float e[PED];
  __shared__ __align__(16) float h[DM];
  const int t = threadIdx.x;
  const int c4 = t & 63;          // float4 column group
  const int rr = t >> 6;          // row slot 0..3
  for (int u = blockIdx.x; u < U; u += gridDim.x){
    const int o0 = offs[u], cnt = counts[u];
    float4 s = {0.f,0.f,0.f,0.f};
    for (int base = 0; base < cnt; base += 512){
      const int cc = min(cnt - base, 512);
      __syncthreads();                               // gl reuse guard
      for (int j = t; j < cc; j += 256) gl[j] = gidx[o0 + base + j];
      __syncthreads();
      int j = rr;
      for (; j + 8 <= cc; j += 8){                   // 2 rows in flight per thread
        const int r0 = gl[j], r1 = gl[j+4];
        float4 v0 = *reinterpret_cast<const float4*>(&feats[(size_t)r0*DM + c4*4]);
        float4 v1 = *reinterpret_cast<const float4*>(&feats[(size_t)r1*DM + c4*4]);
        s.x += v0.x + v1.x; s.y += v0.y + v1.y;
        s.z += v0.z + v1.z; s.w += v0.w + v1.w;
      }
      for (; j < cc; j += 4){
        float4 v0 = *reinterpret_cast<const float4*>(&feats[(size_t)gl[j]*DM + c4*4]);
        s.x += v0.x; s.y += v0.y; s.z += v0.z; s.w += v0.w;
      }
    }
    red[t] = s;
    if (t < PED)
      e[t] = embed_elem(uv[u*3], uv[u*3+1], uv[u*3+2], t);
    __syncthreads();
    if (rr == 0){
      float4 a = red[c4], b = red[64+c4], c = red[128+c4], d = red[192+c4];
      a.x += b.x + c.x + d.x; a.y += b.y + c.y + d.y;
      a.z += b.z + c.z + d.z; a.w += b.w + c.w + d.w;
      red[c4] = a;
    }
    __syncthreads();
    const float sum = reinterpret_cast<const float*>(red)[t];   // column t total
    // PE MLP (thread t owns output column t)
    float a1 = pb1[t];
    const float* w1 = pw1 + t*PED;
    for (int k = 0; k < PED; ++k) a1 += w1[k]*e[k];
    h[t] = lrelu(a1);
    __syncthreads();
    float a2 = pb2[t];
    const float* w2 = pw2 + (size_t)t*DM;
    for (int k = 0; k < DM; k += 4){
      float4 w = *reinterpret_cast<const float4*>(w2+k);
      float4 hv = *reinterpret_cast<const float4*>(&h[k]);
      a2 += w.x*hv.x + w.y*hv.y + w.z*hv.z + w.w*hv.w;
    }
    x[(size_t)u*DM + t] = sum + a2;
    __syncthreads();
  }
}

// ---------------- bf16 MFMA GEMM: C[M][Nn] = act(A_f32[M][K] * Bbf[Nn][K]^T + bias) (+res) ----------------
template<int ACT, bool HASRES>
__global__ __launch_bounds__(256) void gemm_bf(const float* __restrict__ A,
    const short* __restrict__ Bbf, const float* __restrict__ bias,
    const float* __restrict__ res, float* __restrict__ C,
    const int K, const int Nn, const int* __restrict__ pU){
  const int M = *pU;
  const int r0 = blockIdx.x * 64;
  if (r0 >= M) return;
  const int n0 = blockIdx.y * 64;
  __shared__ __align__(16) short Al[64*32];
  const int tid = threadIdx.x;
  const int wid = tid >> 6, lane = tid & 63;
  const int l15 = lane & 15, l4 = lane >> 4;
  f32x4 acc[4];
  #pragma unroll
  for (int nt = 0; nt < 4; ++nt) acc[nt] = (f32x4){0.f,0.f,0.f,0.f};
  const int nk = K >> 5;
  const int srow = tid >> 2, se8 = (tid & 3) * 8;
  const int arowc = min(r0 + srow, M-1);
  for (int kc = 0; kc < nk; ++kc){
    {
      const float* ap = A + (size_t)arowc*K + kc*32 + se8;
      f32x4 a0 = *(const f32x4*)ap;
      f32x4 a1 = *(const f32x4*)(ap + 4);
      bf16x8 av;
      av[0]=f2b(a0[0]); av[1]=f2b(a0[1]); av[2]=f2b(a0[2]); av[3]=f2b(a0[3]);
      av[4]=f2b(a1[0]); av[5]=f2b(a1[1]); av[6]=f2b(a1[2]); av[7]=f2b(a1[3]);
      *(bf16x8*)&Al[(srow*32 + se8) ^ ((srow & 7) << 3)] = av;
    }
    __syncthreads();
    const int ar = 16*wid + l15;
    bf16x8 af = *(const bf16x8*)&Al[(ar*32 + 8*l4) ^ ((ar & 7) << 3)];
    #pragma unroll
    for (int nt = 0; nt < 4; ++nt){
      const short* bp = Bbf + (size_t)(n0 + 16*nt + l15)*K + kc*32 + 8*l4;
      bf16x8 bfr = *(const bf16x8*)bp;
      acc[nt] = mfma16(af, bfr, acc[nt]);
    }
    __syncthreads();
  }
  #pragma unroll
  for (int nt = 0; nt < 4; ++nt){
    const int col = n0 + 16*nt + l15;
    const float bv = bias[col];
    #pragma unroll
    for (int r = 0; r < 4; ++r){
      const int row = r0 + 16*wid + 4*l4 + r;
      if (row < M){
        float v = acc[nt][r] + bv;
        if (ACT == 1) v = fmaxf(v, 0.f);
        if (HASRES) v += res[(size_t)row*Nn + col];
        C[(size_t)row*Nn + col] = v;
      }
    }
  }
}

// ---------------- MFMA flash attention (swapped S^T = K*Q^T), 4 waves x 16 queries ----------------
__global__ __launch_bounds__(256) void attn_mfma(const float* __restrict__ qkv,
                                                 float* __restrict__ y, const int* __restrict__ pU){
  const int U = *pU;
  const int bid = blockIdx.x;
  const int h = bid & 7, qt = bid >> 3;
  const int q0 = qt * 64;
  const int tid = threadIdx.x;
  const int wid = tid >> 6, lane = tid & 63;
  const int l15 = lane & 15, l4 = lane >> 4;
  __shared__ __align__(16) short Kl[64*32];     // K tile, row-major [key][dh], swizzled
  __shared__ __align__(16) short Vt[32*64];     // V^T tile [dh][key], swizzled
  __shared__ __align__(16) short Pl[4][64*16];  // per-wave P^T [key][q]

  const int qrow = min(q0 + 16*wid + l15, U-1);
  const float* qp = qkv + (size_t)qrow*768 + h*DHD + 8*l4;
  bf16x8 qf;
  {
    f32x4 q0v = *(const f32x4*)qp;
    f32x4 q1v = *(const f32x4*)(qp + 4);
    qf[0]=f2b(q0v[0]*SCL); qf[1]=f2b(q0v[1]*SCL); qf[2]=f2b(q0v[2]*SCL); qf[3]=f2b(q0v[3]*SCL);
    qf[4]=f2b(q1v[0]*SCL); qf[5]=f2b(q1v[1]*SCL); qf[6]=f2b(q1v[2]*SCL); qf[7]=f2b(q1v[3]*SCL);
  }
  f32x4 o0 = (f32x4){0.f,0.f,0.f,0.f}, o1 = (f32x4){0.f,0.f,0.f,0.f};
  float mrun = -INFINITY, lrun = 0.f;
  const int srow = tid >> 2, se8 = (tid & 3) * 8;
  const int ntile = (U + 63) >> 6;
  for (int kt = 0; kt < ntile; ++kt){
    const int kb = kt * 64;
    {
      const int krow = min(kb + srow, U-1);
      const float* kp = qkv + (size_t)krow*768 + DM + h*DHD + se8;
      f32x4 k0 = *(const f32x4*)kp;
      f32x4 k1 = *(const f32x4*)(kp + 4);
      bf16x8 kv;
      kv[0]=f2b(k0[0]); kv[1]=f2b(k0[1]); kv[2]=f2b(k0[2]); kv[3]=f2b(k0[3]);
      kv[4]=f2b(k1[0]); kv[5]=f2b(k1[1]); kv[6]=f2b(k1[2]); kv[7]=f2b(k1[3]);
      *(bf16x8*)&Kl[(srow*32 + se8) ^ ((srow & 7) << 3)] = kv;
      const float* vp = qkv + (size_t)krow*768 + 2*DM + h*DHD + se8;
      f32x4 v0 = *(const f32x4*)vp;
      f32x4 v1 = *(const f32x4*)(vp + 4);
      #pragma unroll
      for (int j = 0; j < 8; ++j){
        const int d = se8 + j;
        const float vv = (j < 4) ? v0[j & 3] : v1[j & 3];
        Vt[(d*64 + srow) ^ ((d & 7) << 3)] = f2b(vv);
      }
    }
    __syncthreads();
    float s[16];
    #pragma unroll
    for (int nt = 0; nt < 4; ++nt){
      const int row = 16*nt + l15;
      bf16x8 kf = *(const bf16x8*)&Kl[(row*32 + 8*l4) ^ ((row & 7) << 3)];
      f32x4 d = mfma16(kf, qf, (f32x4){0.f,0.f,0.f,0.f});
      const int kbase = kb + 16*nt + 4*l4;
      #pragma unroll
      for (int r = 0; r < 4; ++r)
        s[nt*4 + r] = (kbase + r < U) ? d[r] : -INFINITY;
    }
    float cm = s[0];
    #pragma unroll
    for (int i = 1; i < 16; ++i) cm = fmaxf(cm, s[i]);
    cm = fmaxf(cm, __shfl_xor(cm, 16));
    cm = fmaxf(cm, __shfl_xor(cm, 32));
    const float mnew = fmaxf(mrun, cm);
    const float f = __expf(mrun - mnew);
    float ls = 0.f;
    #pragma unroll
    for (int i = 0; i < 16; ++i){ s[i] = __expf(s[i] - mnew); ls += s[i]; }
    ls += __shfl_xor(ls, 16);
    ls += __shfl_xor(ls, 32);
    lrun = lrun * f + ls;
    o0 = o0 * f; o1 = o1 * f;
    mrun = mnew;
    #pragma unroll
    for (int nt = 0; nt < 4; ++nt)
      #pragma unroll
      for (int r = 0; r < 4; ++r){
        const int row = 16*nt + 4*l4 + r;
        Pl[wid][(row*16 + l15) ^ (((row >> 2) & 3) << 2)] = f2b(s[nt*4 + r]);
      }
    __syncthreads();
    #pragma unroll
    for (int kc = 0; kc < 2; ++kc){
      bf16x8 pf;
      #pragma unroll
      for (int j = 0; j < 8; ++j){
        const int row = 32*kc + 8*l4 + j;
        pf[j] = Pl[wid][(row*16 + l15) ^ (((row >> 2) & 3) << 2)];
      }
      {
        const int row = l15;
        bf16x8 vf = *(const bf16x8*)&Vt[(row*64 + 32*kc + 8*l4) ^ ((row & 7) << 3)];
        o0 = mfma16(vf, pf, o0);
      }
      {
        const int row = 16 + l15;
        bf16x8 vf = *(const bf16x8*)&Vt[(row*64 + 32*kc + 8*l4) ^ ((row & 7) << 3)];
        o1 = mfma16(vf, pf, o1);
      }
    }
    __syncthreads();
  }
  const float invl = 1.f / lrun;
  const int qg = q0 + 16*wid + l15;
  if (qg < U){
    float* yp = y + (size_t)qg*DM + h*DHD;
    #pragma unroll
    for (int r = 0; r < 4; ++r){
      yp[4*l4 + r]      = o0[r] * invl;
      yp[16 + 4*l4 + r] = o1[r] * invl;
    }
  }
}

// ---------------- LayerNorm ----------------
__global__ __launch_bounds__(256) void ln_kernel(const float* __restrict__ in,
    const float* __restrict__ w, const float* __restrict__ b,
    float* __restrict__ out, const int* __restrict__ pU){
  const int U = *pU;
  const int t = threadIdx.x;
  const int wid = t >> 6;
  __shared__ float red[4];
  for (int u = blockIdx.x; u < U; u += gridDim.x){
    float v = in[(size_t)u*DM + t];
    float s = wred(v);
    if ((t & 63) == 0) red[wid] = s;
    __syncthreads();
    float mean = (red[0]+red[1]+red[2]+red[3]) * (1.f/DM);
    __syncthreads();
    float d = v - mean;
    float sq = wred(d*d);
    if ((t & 63) == 0) red[wid] = sq;
    __syncthreads();
    float var = (red[0]+red[1]+red[2]+red[3]) * (1.f/DM);
    out[(size_t)u*DM + t] = d * (1.0f/sqrtf(var + EPSF)) * w[t] + b[t];
    __syncthreads();
  }
}

// ---------------- per-gaussian delta MLP, voxel-sorted order (gather locality) ----------------
// Block b handles sorted positions [64b, 64b+64): gid = gidx[pos]. Within a block the
// ~1-2 distinct voxels make rc/x gathers L1-broadcast instead of L3-scatter.
__global__ __launch_bounds__(256) void delta_mfma(const float* __restrict__ centres,
   const int* __restrict__ inv, const int* __restrict__ gidx,
   const float* __restrict__ x, const float* __restrict__ rc,
   const short* __restrict__ w1abf, const short* __restrict__ w2bf,
   const float* __restrict__ db2, float* __restrict__ out){
  __shared__ __align__(16) float cs[64][3];
  __shared__ int ivl[64];
  __shared__ int sg[64];
  __shared__ __align__(16) short hl[64*256];    // hidden tile [g][256] bf16, swizzled
  const int tid = threadIdx.x;
  const int wid = tid >> 6, lane = tid & 63;
  const int l15 = lane & 15, l4 = lane >> 4;
  const int p0 = blockIdx.x * 64;
  if (tid < 64){
    const int pos = p0 + tid;
    const int gid = gidx[min(pos, NG-1)];
    sg[tid]  = (pos < NG) ? gid : -1;
    ivl[tid] = inv[gid];
    cs[tid][0] = centres[gid*3];
    cs[tid][1] = centres[gid*3+1];
    cs[tid][2] = centres[gid*3+2];
  }
  __syncthreads();
  // A-fragment (embed) computed directly in registers; lane's gaussian = slot 16*wid + l15
  const int arow = 16*wid + l15;
  const float cx = cs[arow][0], cy = cs[arow][1], cz = cs[arow][2];
  bf16x8 ef[2];
  #pragma unroll
  for (int kc = 0; kc < 2; ++kc)
    #pragma unroll
    for (int jj = 0; jj < 8; ++jj){
      const int j = kc*32 + 8*l4 + jj;
      ef[kc][jj] = f2b(j < PED ? embed_elem(cx, cy, cz, j) : 0.f);
    }
  const int glb = 16*wid + 4*l4;
  const int rv0 = ivl[glb], rv1 = ivl[glb+1], rv2 = ivl[glb+2], rv3 = ivl[glb+3];
  // layer 1: h = lrelu(rc[vox] + e @ W1a^T)
  #pragma unroll
  for (int nt = 0; nt < 16; ++nt){
    const int c = 16*nt + l15;
    f32x4 a;
    a[0] = rc[(size_t)rv0*DM + c];
    a[1] = rc[(size_t)rv1*DM + c];
    a[2] = rc[(size_t)rv2*DM + c];
    a[3] = rc[(size_t)rv3*DM + c];
    #pragma unroll
    for (int kc = 0; kc < 2; ++kc){
      const bf16x8 bfr = *(const bf16x8*)&w1abf[(16*nt + l15)*64 + kc*32 + 8*l4];
      a = mfma16(ef[kc], bfr, a);
    }
    #pragma unroll
    for (int r = 0; r < 4; ++r){
      const int row = glb + r;
      hl[(row*256 + c) ^ ((row & 7) << 3)] = f2b(lrelu(a[r]));
    }
  }
  __syncthreads();
  // layer 2: out = x[vox] + b2 + h @ W2^T   (two column halves to cap VGPR)
  bf16x8 hf[8];
  #pragma unroll
  for (int kc = 0; kc < 8; ++kc){
    const int row = 16*wid + l15;
    hf[kc] = *(const bf16x8*)&hl[(row*256 + kc*32 + 8*l4) ^ ((row & 7) << 3)];
  }
  const int g0 = sg[glb], g1 = sg[glb+1], g2 = sg[glb+2], g3 = sg[glb+3];
  #pragma unroll
  for (int half = 0; half < 2; ++half){
    f32x4 acc[8];
    #pragma unroll
    for (int q = 0; q < 8; ++q){
      const int c = half*128 + 16*q + l15;
      const float bv = db2[c];
      acc[q][0] = x[(size_t)rv0*DM + c] + bv;
      acc[q][1] = x[(size_t)rv1*DM + c] + bv;
      acc[q][2] = x[(size_t)rv2*DM + c] + bv;
      acc[q][3] = x[(size_t)rv3*DM + c] + bv;
    }
    #pragma unroll
    for (int kc = 0; kc < 8; ++kc)
      #pragma unroll
      for (int q = 0; q < 8; ++q){
        const int n = half*128 + 16*q + l15;
        const bf16x8 bfr = *(const bf16x8*)&w2bf[(size_t)n*256 + kc*32 + 8*l4];
        acc[q] = mfma16(hf[kc], bfr, acc[q]);
      }
    #pragma unroll
    for (int q = 0; q < 8; ++q){
      const int c = half*128 + 16*q + l15;
      if (g0 >= 0) out[(size_t)g0*DM + c] = acc[q][0];
      if (g1 >= 0) out[(size_t)g1*DM + c] = acc[q][1];
      if (g2 >= 0) out[(size_t)g2*DM + c] = acc[q][2];
      if (g3 >= 0) out[(size_t)g3*DM + c] = acc[q][3];
    }
  }
}

extern "C" void kernel_launch(void* const* d_in, const int* in_sizes, int n_in,
                              void* d_out, int out_size, void* d_ws, size_t ws_size,
                              hipStream_t stream){
  (void)in_sizes; (void)n_in; (void)out_size; (void)ws_size;
  const float* centres = (const float*)d_in[0];
  const float* feats   = (const float*)d_in[1];
  const int*   inv     = (const int*)d_in[2];
  const int*   pU      = (const int*)d_in[3];
  const float* ipw = (const float*)d_in[4];
  const float* ipb = (const float*)d_in[5];
  const float* opw = (const float*)d_in[6];
  const float* opb = (const float*)d_in[7];
  const float* l1w = (const float*)d_in[8];
  const float* l1b = (const float*)d_in[9];
  const float* l2w = (const float*)d_in[10];
  const float* l2b = (const float*)d_in[11];
  const float* n1w = (const float*)d_in[12];
  const float* n1b = (const float*)d_in[13];
  const float* n2w = (const float*)d_in[14];
  const float* n2b = (const float*)d_in[15];
  const float* pw1 = (const float*)d_in[16];
  const float* pb1 = (const float*)d_in[17];
  const float* pw2 = (const float*)d_in[18];
  const float* pb2 = (const float*)d_in[19];
  const float* dw1 = (const float*)d_in[20];
  const float* db1 = (const float*)d_in[21];
  const float* dw2 = (const float*)d_in[22];
  const float* db2 = (const float*)d_in[23];
  float* out = (float*)d_out;

  char* ws = (char*)d_ws;
  size_t off = 0;
  auto take = [&](size_t bytes)->char*{
    char* p = ws + off; off += (bytes + 255) & ~(size_t)255; return p;
  };
  float* xb   = (float*)take((size_t)UP*DM*4);
  float* yb   = (float*)take((size_t)UP*DM*4);
  float* big  = (float*)take((size_t)UP*DFF*4);
  float* rcb  = (float*)take((size_t)UP*DM*4);
  float* uv   = (float*)take((size_t)UP*3*4);
  int* counts = (int*)take((size_t)2*UP*4);
  int* cursor = counts + UP;
  int* offs   = (int*)take((size_t)UP*4);
  int* gidx   = (int*)take((size_t)NG*4);
  short* ipwbf  = (short*)take((size_t)2*768*256*2);
  short* opwbf  = (short*)take((size_t)2*256*256*2);
  short* l1wbf  = (short*)take((size_t)2*1024*256*2);
  short* l2wbf  = (short*)take((size_t)2*256*1024*2);
  short* dw2bf  = (short*)take((size_t)256*256*2);
  short* dw1bbf = (short*)take((size_t)256*256*2);
  short* dw1abf = (short*)take((size_t)256*64*2);

  zero_kernel<<<(2*UP + 255)/256, 256, 0, stream>>>(counts, 2*UP);
  prep_kernel<<<1024, 256, 0, stream>>>(centres, inv, counts, uv);
  scan_kernel<<<1, 1024, 0, stream>>>(counts, offs, pU);
  scatter_kernel<<<1024, 256, 0, stream>>>(inv, offs, cursor, gidx);
  cvt_weights<<<dim3(2048, 7), 256, 0, stream>>>(ipw, opw, l1w, l2w, dw1, dw2,
                                                 ipwbf, opwbf, l1wbf, l2wbf,
                                                 dw2bf, dw1bbf, dw1abf);
  agg_pe_kernel<<<MAXU, 256, 0, stream>>>(feats, gidx, offs, counts, uv,
                                          pw1, pb1, pw2, pb2, xb, pU);

  for (int l = 0; l < NLAY; ++l){
    gemm_bf<0,false><<<dim3(NQT,12), 256, 0, stream>>>(xb, ipwbf + (size_t)l*768*256,
        ipb + (size_t)l*768, nullptr, big, DM, 3*DM, pU);
    attn_mfma<<<8*NQT, 256, 0, stream>>>(big, yb, pU);
    gemm_bf<0,true><<<dim3(NQT,4), 256, 0, stream>>>(yb, opwbf + (size_t)l*256*256,
        opb + (size_t)l*DM, xb, big, DM, DM, pU);
    ln_kernel<<<1024, 256, 0, stream>>>(big, n1w + (size_t)l*DM, n1b + (size_t)l*DM, xb, pU);
    gemm_bf<1,false><<<dim3(NQT,16), 256, 0, stream>>>(xb, l1wbf + (size_t)l*1024*256,
        l1b + (size_t)l*DFF, nullptr, big, DM, DFF, pU);
    gemm_bf<0,true><<<dim3(NQT,4), 256, 0, stream>>>(big, l2wbf + (size_t)l*256*1024,
        l2b + (size_t)l*DM, xb, yb, DFF, DM, pU);
    ln_kernel<<<1024, 256, 0, stream>>>(yb, n2w + (size_t)l*DM, n2b + (size_t)l*DM, xb, pU);
  }

  gemm_bf<0,false><<<dim3(NQT,4), 256, 0, stream>>>(xb, dw1bbf, db1, nullptr, rcb, DM, DM, pU);
  delta_mfma<<<NDBLK, 256, 0, stream>>>(centres, inv, gidx, xb, rcb, dw1abf, dw2bf, db2, out);
}